// Round 6
// baseline (258.437 us; speedup 1.0000x reference)
//
#include <hip/hip_runtime.h>
#include <stdint.h>

#define NBATCH 32
#define NBINS  32768          // 15-bit score buckets
#define BSHIFT 17             // ordbits >> 17 -> bucket
#define CAP    4096

typedef unsigned long long u64;
typedef unsigned int u32;
typedef float f4 __attribute__((ext_vector_type(4)));

struct WsHdr {
  u64 keysel[NBATCH];  // selected 56-bit k-th smallest key per segment
  int counts[NBATCH];
  int starts[NBATCH];
  int ndrop[NBATCH];
  int sel[NBATCH];     // selected bucket (NBINS = none/empty segment)
  int krem2[NBATCH];   // residual rank within selected bucket
  int ccount[NBATCH];  // candidate counts
  int pad[NBATCH];
};
// ws layout: WsHdr | u32 hist[NBATCH*NBINS] (4MB) | u64 cand[NBATCH*CAP] (1MB)

// monotone float->uint transform
__device__ __forceinline__ u32 ordbits(float s) {
  u32 u = __float_as_uint(s);
  return (u & 0x80000000u) ? ~u : (u | 0x80000000u);
}

// ---------------- fast path ----------------

// zero hist region; block 0's first wave computes per-segment bounds by
// binary search on the sorted batch array (no atomics, no full pass).
__global__ void k_init(const int* __restrict__ batch, int n,
                       WsHdr* ws, f4* __restrict__ histz, int nz16) {
  int stride = gridDim.x * blockDim.x;
  f4 z = {0.f, 0.f, 0.f, 0.f};
  for (int i = blockIdx.x * blockDim.x + threadIdx.x; i < nz16; i += stride)
    histz[i] = z;
  if (blockIdx.x == 0 && threadIdx.x < NBATCH) {
    int b = threadIdx.x;
    int lo = 0, hi = n;                    // lower_bound(batch, b)
    while (lo < hi) { int mid = (lo + hi) >> 1; if (batch[mid] < b) lo = mid + 1; else hi = mid; }
    int start = lo;
    int nxt = __shfl_down(start, 1, 32);
    if (b == NBATCH - 1) nxt = n;
    int c = nxt - start;
    ws->starts[b] = start;
    ws->counts[b] = c;
    ws->ndrop[b]  = c >> 1;                // floor(c*0.5) exact
    ws->ccount[b] = 0;
  }
}

// one global atomic per point, nothing else
__global__ void k_hist(const int* __restrict__ batch, const float* __restrict__ scores,
                       int n, u32* __restrict__ hist) {
  int i = blockIdx.x * blockDim.x + threadIdx.x;
  if (i < n) {
    u32 ob = ordbits(scores[i]);
    atomicAdd(&hist[((size_t)batch[i] << 15) | (ob >> BSHIFT)], 1u);
  }
}

// two-level select; level 1 is wave-cooperative (coalesced) stripe sums
__global__ void k_pick(const u32* __restrict__ hist, WsHdr* ws) {
  __shared__ int sc[256];
  __shared__ int sh_w, sh_krem;
  int b = blockIdx.x, t = threadIdx.x;
  const u32* h = hist + ((size_t)b << 15);
  int cnt = ws->counts[b];
  if (cnt == 0) {
    if (t == 0) { ws->sel[b] = NBINS; ws->krem2[b] = 0; }
    return;
  }
  int krem = ws->ndrop[b];
  int wave = t >> 6, lane = t & 63;
  // stripe s covers bins [s*128, s*128+128); wave w handles stripes w*64..w*64+63
  for (int s = wave * 64; s < wave * 64 + 64; ++s) {
    int v = (int)h[s * 128 + lane] + (int)h[s * 128 + 64 + lane];  // coalesced
    for (int off = 32; off > 0; off >>= 1) v += __shfl_down(v, off, 64);
    if (lane == 0) sc[s] = v;
  }
  __syncthreads();
  int s0 = sc[t];
  for (int off = 1; off < 256; off <<= 1) {          // Hillis-Steele inclusive scan
    int v = (t >= off) ? sc[t - off] : 0;
    __syncthreads(); sc[t] += v; __syncthreads();
  }
  int excl = sc[t] - s0;
  if (krem >= excl && krem < excl + s0) { sh_w = t; sh_krem = krem - excl; }
  __syncthreads();
  int W = sh_w, krem1 = sh_krem;
  // level 2: 128 bins of winning stripe, coalesced
  int c = (t < 128) ? (int)h[W * 128 + t] : 0;
  sc[t] = c; __syncthreads();
  for (int off = 1; off < 256; off <<= 1) {
    int v = (t >= off) ? sc[t - off] : 0;
    __syncthreads(); sc[t] += v; __syncthreads();
  }
  int excl2 = sc[t] - c;
  if (t < 128 && krem1 >= excl2 && krem1 < excl2 + c) {
    ws->sel[b] = W * 128 + t;
    ws->krem2[b] = krem1 - excl2;
  }
}

__global__ void k_compact(const int* __restrict__ batch, const float* __restrict__ scores,
                          int n, WsHdr* ws, u64* __restrict__ cand) {
  int i = blockIdx.x * blockDim.x + threadIdx.x;
  if (i < n) {
    int b = batch[i];
    u32 ob = ordbits(scores[i]);
    if ((int)(ob >> BSHIFT) == ws->sel[b]) {
      int p = atomicAdd(&ws->ccount[b], 1);
      if (p < CAP)
        cand[(size_t)b * CAP + p] = ((u64)ob << 24) | (u32)(i - ws->starts[b]);
    }
  }
}

__global__ void k_final(WsHdr* ws, const u64* __restrict__ cand) {
  __shared__ u64 ck[CAP];
  int b = blockIdx.x, t = threadIdx.x;
  int m = ws->ccount[b]; if (m > CAP) m = CAP;
  if (m == 0) { if (t == 0) ws->keysel[b] = 0ull; return; }
  for (int j = t; j < m; j += 256) ck[j] = cand[(size_t)b * CAP + j];
  __syncthreads();
  int krem = ws->krem2[b];
  for (int j = t; j < m; j += 256) {
    u64 key = ck[j];
    int r = 0;
    for (int q = 0; q < m; ++q) r += (ck[q] < key);  // distinct keys -> distinct ranks
    if (r == krem) ws->keysel[b] = key;
  }
}

// ---------------- fallback path (small ws): round-1 passing kernels ----------------

__global__ void k_zero(WsHdr* ws) {
  int t = threadIdx.x;
  if (t < NBATCH) ws->counts[t] = 0;
}

__global__ void k_hist_fb(const int* __restrict__ batch, int n, WsHdr* ws) {
  __shared__ int h[NBATCH];
  if (threadIdx.x < NBATCH) h[threadIdx.x] = 0;
  __syncthreads();
  int stride = gridDim.x * blockDim.x;
  for (int i = blockIdx.x * blockDim.x + threadIdx.x; i < n; i += stride)
    atomicAdd(&h[batch[i]], 1);
  __syncthreads();
  if (threadIdx.x < NBATCH) atomicAdd(&ws->counts[threadIdx.x], h[threadIdx.x]);
}

__global__ void k_scan_fb(WsHdr* ws) {
  if (threadIdx.x == 0) {
    int acc = 0;
    for (int b = 0; b < NBATCH; ++b) {
      int c = ws->counts[b];
      ws->starts[b] = acc;
      ws->ndrop[b] = c >> 1;
      acc += c;
    }
  }
}

__global__ void k_select_fb(const float* __restrict__ scores, WsHdr* ws) {
  __shared__ u32 hist[256];
  __shared__ u64 sh_prefix;
  __shared__ int sh_krem;
  int b = blockIdx.x;
  int start = ws->starts[b];
  int cnt = ws->counts[b];
  if (threadIdx.x == 0) { sh_prefix = 0ull; sh_krem = ws->ndrop[b]; }
  __syncthreads();
  for (int shift = 48; shift >= 0; shift -= 8) {
    for (int j = threadIdx.x; j < 256; j += blockDim.x) hist[j] = 0;
    __syncthreads();
    u64 prefix = sh_prefix;
    for (int idx = threadIdx.x; idx < cnt; idx += blockDim.x) {
      u64 key = ((u64)ordbits(scores[start + idx]) << 24) | (u32)idx;
      if ((key >> (shift + 8)) == prefix)
        atomicAdd(&hist[(u32)(key >> shift) & 255u], 1u);
    }
    __syncthreads();
    if (threadIdx.x == 0) {
      int krem = sh_krem;
      u32 cum = 0, sel = 255;
      for (int j = 0; j < 256; ++j) {
        u32 c = hist[j];
        if ((u32)krem < cum + c) { sel = (u32)j; krem -= (int)cum; break; }
        cum += c;
      }
      sh_prefix = (prefix << 8) | sel;
      sh_krem = krem;
    }
    __syncthreads();
  }
  if (threadIdx.x == 0) ws->keysel[b] = sh_prefix;
}

// ---------------- apply: EXACT round-3 form (A/B control) ----------------
__global__ void k_apply(const float4* __restrict__ feats4,
                        const int* __restrict__ batch,
                        const float* __restrict__ scores,
                        const WsHdr* __restrict__ ws,
                        float4* __restrict__ out4, int n) {
  __shared__ float m[16];
  int t = threadIdx.x;
  int pl = t >> 4, ch = t & 15;
  int i = blockIdx.x * 16 + pl;
  if (ch == 0) {
    float keep = 0.f;
    if (i < n) {
      int b = batch[i];
      int start = ws->starts[b];
      u64 key = ((u64)ordbits(scores[i]) << 24) | (u32)(i - start);
      keep = (key >= ws->keysel[b]) ? 1.f : 0.f;
    }
    m[pl] = keep;
  }
  __syncthreads();
  if (i < n) {
    size_t off = (size_t)i * 16 + (size_t)ch;
    float4 v = feats4[off];
    float s = m[pl];
    v.x *= s; v.y *= s; v.z *= s; v.w *= s;
    out4[off] = v;
  }
}

extern "C" void kernel_launch(void* const* d_in, const int* in_sizes, int n_in,
                              void* d_out, int out_size, void* d_ws, size_t ws_size,
                              hipStream_t stream) {
  const float* feats  = (const float*)d_in[0];
  const int*   batch  = (const int*)d_in[1];
  const float* scores = (const float*)d_in[2];
  float* out = (float*)d_out;
  int n = in_sizes[1];
  WsHdr* ws = (WsHdr*)d_ws;

  const size_t hist_bytes = (size_t)NBATCH * NBINS * sizeof(u32);   // 4 MB
  const size_t cand_bytes = (size_t)NBATCH * CAP * sizeof(u64);     // 1 MB
  const size_t need = sizeof(WsHdr) + hist_bytes + cand_bytes;

  if (ws_size >= need) {
    u32* hist = (u32*)((char*)d_ws + sizeof(WsHdr));
    u64* cand = (u64*)((char*)d_ws + sizeof(WsHdr) + hist_bytes);
    int nz16 = (int)(hist_bytes / 16);
    int pb = (n + 255) / 256;
    k_init   <<<2048, 256, 0, stream>>>(batch, n, ws, (f4*)hist, nz16);
    k_hist   <<<pb, 256, 0, stream>>>(batch, scores, n, hist);
    k_pick   <<<NBATCH, 256, 0, stream>>>(hist, ws);
    k_compact<<<pb, 256, 0, stream>>>(batch, scores, n, ws, cand);
    k_final  <<<NBATCH, 256, 0, stream>>>(ws, cand);
  } else {
    k_zero     <<<1, 64, 0, stream>>>(ws);
    k_hist_fb  <<<1024, 256, 0, stream>>>(batch, n, ws);
    k_scan_fb  <<<1, 64, 0, stream>>>(ws);
    k_select_fb<<<NBATCH, 256, 0, stream>>>(scores, ws);
  }

  int blocks = (n + 15) / 16;   // 16 rows per block, 16 float4 per row
  k_apply<<<blocks, 256, 0, stream>>>((const float4*)feats, batch, scores, ws,
                                      (float4*)out, n);
}

// Round 7
// 204.380 us; speedup vs baseline: 1.2645x; 1.2645x over previous
//
#include <hip/hip_runtime.h>
#include <stdint.h>

#define NBATCH 32
#define NBINS  65536          // 16-bit score buckets
#define BSHIFT 16
#define NSTRIPE 256           // stripes per segment (256 bins each)
#define CAP    4096

typedef unsigned long long u64;
typedef unsigned int u32;
typedef float f4 __attribute__((ext_vector_type(4)));

struct WsHdr {
  u64 keysel[NBATCH];  // selected 56-bit k-th smallest key per segment
  int counts[NBATCH];
  int starts[NBATCH];
  int ndrop[NBATCH];
  int sel[NBATCH];     // selected bucket (NBINS = none/empty segment)
  int krem2[NBATCH];   // residual rank within selected bucket
  int ccount[NBATCH];  // candidate counts
  int pad[NBATCH];
};
// ws: WsHdr | u32 hist[NBATCH*NBINS] (8MB) | u64 cand[NBATCH*CAP] (1MB) | u32 stripes[NBATCH*NSTRIPE] (32KB)

__device__ __forceinline__ u32 ordbits(float s) {
  u32 u = __float_as_uint(s);
  return (u & 0x80000000u) ? ~u : (u | 0x80000000u);
}

// ---------------- fast path ----------------

// zero hist (grid-stride, full BW) + header counters (block 0)
__global__ void k_zero(WsHdr* ws, f4* __restrict__ histz, int nz16) {
  int stride = gridDim.x * blockDim.x;
  f4 z = {0.f, 0.f, 0.f, 0.f};
  for (int i = blockIdx.x * blockDim.x + threadIdx.x; i < nz16; i += stride)
    histz[i] = z;
  if (blockIdx.x == 0 && threadIdx.x < NBATCH) {
    ws->counts[threadIdx.x] = 0;
    ws->ccount[threadIdx.x] = 0;
  }
}

// global-atomic bucket histogram + wave-aggregated segment counts.
// batch is sorted -> nearly every wave is batch-uniform -> 1 LDS atomic/wave.
__global__ void k_hist(const int* __restrict__ batch, const float* __restrict__ scores,
                       int n, u32* __restrict__ hist, WsHdr* ws) {
  __shared__ int h[NBATCH];
  if (threadIdx.x < NBATCH) h[threadIdx.x] = 0;
  __syncthreads();
  int i = blockIdx.x * blockDim.x + threadIdx.x;
  if (i < n) {
    int b = batch[i];
    u32 ob = ordbits(scores[i]);
    atomicAdd(&hist[((size_t)b << BSHIFT) | (ob >> BSHIFT)], 1u);
    u64 act = __ballot(1);                       // active-lane mask
    int lead = (int)__ffsll((long long)act) - 1;
    int b0 = __shfl(b, lead, 64);
    bool uni = (__ballot(b == b0) == act);
    if (uni) {
      if ((threadIdx.x & 63) == lead) atomicAdd(&h[b0], (int)__popcll(act));
    } else {
      atomicAdd(&h[b], 1);
    }
  }
  __syncthreads();
  if (threadIdx.x < NBATCH && h[threadIdx.x] != 0)
    atomicAdd(&ws->counts[threadIdx.x], h[threadIdx.x]);
}

__global__ void k_scan(WsHdr* ws) {
  if (threadIdx.x == 0) {
    int acc = 0;
    for (int b = 0; b < NBATCH; ++b) {
      int c = ws->counts[b];
      ws->starts[b] = acc;
      ws->ndrop[b] = c >> 1;   // floor(c*0.5) exact
      acc += c;
    }
  }
}

// all 8192 stripe-sums (256 bins each) computed cooperatively at full BW.
// one stripe per wave-iteration: lane reads 4 coalesced u32, 6-step shfl reduce.
__global__ void k_stripes(const u32* __restrict__ hist, u32* __restrict__ stripes) {
  int wave = (blockIdx.x * blockDim.x + threadIdx.x) >> 6;
  int lane = threadIdx.x & 63;
  int nwaves = (gridDim.x * blockDim.x) >> 6;
  for (int g = wave; g < NBATCH * NSTRIPE; g += nwaves) {
    const u32* p = hist + (size_t)g * 256;
    int v = (int)p[lane] + (int)p[64 + lane] + (int)p[128 + lane] + (int)p[192 + lane];
    for (int off = 32; off > 0; off >>= 1) v += __shfl_down(v, off, 64);
    if (lane == 0) stripes[g] = (u32)v;
  }
}

// per-segment: LDS scan of precomputed stripes -> winning stripe; one coalesced
// 1KB read of its 256 bins -> LDS scan -> winning bin + residual rank.
__global__ void k_pick2(const u32* __restrict__ hist, const u32* __restrict__ stripes,
                        WsHdr* ws) {
  __shared__ int sc[256];
  __shared__ int sh_w, sh_krem;
  int b = blockIdx.x, t = threadIdx.x;
  int cnt = ws->counts[b];
  if (cnt == 0) {
    if (t == 0) { ws->sel[b] = NBINS; ws->krem2[b] = 0; }
    return;
  }
  int krem = ws->ndrop[b];
  int s0 = (int)stripes[b * NSTRIPE + t];
  sc[t] = s0; __syncthreads();
  for (int off = 1; off < 256; off <<= 1) {          // Hillis-Steele inclusive scan
    int v = (t >= off) ? sc[t - off] : 0;
    __syncthreads(); sc[t] += v; __syncthreads();
  }
  int excl = sc[t] - s0;
  if (krem >= excl && krem < excl + s0) { sh_w = t; sh_krem = krem - excl; }
  __syncthreads();
  int W = sh_w, krem1 = sh_krem;
  int c = (int)hist[((size_t)b << BSHIFT) + W * 256 + t];
  sc[t] = c; __syncthreads();
  for (int off = 1; off < 256; off <<= 1) {
    int v = (t >= off) ? sc[t - off] : 0;
    __syncthreads(); sc[t] += v; __syncthreads();
  }
  int excl2 = sc[t] - c;
  if (krem1 >= excl2 && krem1 < excl2 + c) {
    ws->sel[b] = W * 256 + t;
    ws->krem2[b] = krem1 - excl2;
  }
}

__global__ void k_compact(const int* __restrict__ batch, const float* __restrict__ scores,
                          int n, WsHdr* ws, u64* __restrict__ cand) {
  int i = blockIdx.x * blockDim.x + threadIdx.x;
  if (i < n) {
    int b = batch[i];
    u32 ob = ordbits(scores[i]);
    if ((int)(ob >> BSHIFT) == ws->sel[b]) {
      int p = atomicAdd(&ws->ccount[b], 1);
      if (p < CAP)
        cand[(size_t)b * CAP + p] = ((u64)ob << 24) | (u32)(i - ws->starts[b]);
    }
  }
}

__global__ void k_final(WsHdr* ws, const u64* __restrict__ cand) {
  __shared__ u64 ck[CAP];
  int b = blockIdx.x, t = threadIdx.x;
  int m = ws->ccount[b]; if (m > CAP) m = CAP;
  if (m == 0) { if (t == 0) ws->keysel[b] = 0ull; return; }
  for (int j = t; j < m; j += 256) ck[j] = cand[(size_t)b * CAP + j];
  __syncthreads();
  int krem = ws->krem2[b];
  for (int j = t; j < m; j += 256) {
    u64 key = ck[j];
    int r = 0;
    for (int q = 0; q < m; ++q) r += (ck[q] < key);  // distinct keys -> distinct ranks
    if (r == krem) ws->keysel[b] = key;
  }
}

// ---------------- fallback path (small ws): round-1 passing kernels ----------------

__global__ void k_zero_fb(WsHdr* ws) {
  int t = threadIdx.x;
  if (t < NBATCH) ws->counts[t] = 0;
}

__global__ void k_hist_fb(const int* __restrict__ batch, int n, WsHdr* ws) {
  __shared__ int h[NBATCH];
  if (threadIdx.x < NBATCH) h[threadIdx.x] = 0;
  __syncthreads();
  int stride = gridDim.x * blockDim.x;
  for (int i = blockIdx.x * blockDim.x + threadIdx.x; i < n; i += stride)
    atomicAdd(&h[batch[i]], 1);
  __syncthreads();
  if (threadIdx.x < NBATCH) atomicAdd(&ws->counts[threadIdx.x], h[threadIdx.x]);
}

__global__ void k_select_fb(const float* __restrict__ scores, WsHdr* ws) {
  __shared__ u32 hist[256];
  __shared__ u64 sh_prefix;
  __shared__ int sh_krem;
  int b = blockIdx.x;
  int start = ws->starts[b];
  int cnt = ws->counts[b];
  if (threadIdx.x == 0) { sh_prefix = 0ull; sh_krem = ws->ndrop[b]; }
  __syncthreads();
  for (int shift = 48; shift >= 0; shift -= 8) {
    for (int j = threadIdx.x; j < 256; j += blockDim.x) hist[j] = 0;
    __syncthreads();
    u64 prefix = sh_prefix;
    for (int idx = threadIdx.x; idx < cnt; idx += blockDim.x) {
      u64 key = ((u64)ordbits(scores[start + idx]) << 24) | (u32)idx;
      if ((key >> (shift + 8)) == prefix)
        atomicAdd(&hist[(u32)(key >> shift) & 255u], 1u);
    }
    __syncthreads();
    if (threadIdx.x == 0) {
      int krem = sh_krem;
      u32 cum = 0, sel = 255;
      for (int j = 0; j < 256; ++j) {
        u32 c = hist[j];
        if ((u32)krem < cum + c) { sel = (u32)j; krem -= (int)cum; break; }
        cum += c;
      }
      sh_prefix = (prefix << 8) | sel;
      sh_krem = krem;
    }
    __syncthreads();
  }
  if (threadIdx.x == 0) ws->keysel[b] = sh_prefix;
}

// ---------------- apply (r5 measured-best variant: nt + skip dropped reads) ----------
__global__ void k_apply(const f4* __restrict__ feats4,
                        const int* __restrict__ batch,
                        const float* __restrict__ scores,
                        const WsHdr* __restrict__ ws,
                        f4* __restrict__ out4, int n) {
  int t = threadIdx.x;
  int pl = t >> 4, ch = t & 15;
  int i = blockIdx.x * 16 + pl;
  if (i >= n) return;
  int b = batch[i];                       // 16-lane broadcast loads
  u64 key = ((u64)ordbits(scores[i]) << 24) | (u32)(i - ws->starts[b]);
  size_t off = (size_t)i * 16 + (size_t)ch;
  f4 v;
  if (key >= ws->keysel[b]) {
    v = __builtin_nontemporal_load(feats4 + off);
  } else {
    v = (f4){0.f, 0.f, 0.f, 0.f};
  }
  __builtin_nontemporal_store(v, out4 + off);
}

extern "C" void kernel_launch(void* const* d_in, const int* in_sizes, int n_in,
                              void* d_out, int out_size, void* d_ws, size_t ws_size,
                              hipStream_t stream) {
  const float* feats  = (const float*)d_in[0];
  const int*   batch  = (const int*)d_in[1];
  const float* scores = (const float*)d_in[2];
  float* out = (float*)d_out;
  int n = in_sizes[1];
  WsHdr* ws = (WsHdr*)d_ws;

  const size_t hist_bytes    = (size_t)NBATCH * NBINS * sizeof(u32);    // 8 MB
  const size_t cand_bytes    = (size_t)NBATCH * CAP * sizeof(u64);      // 1 MB
  const size_t stripe_bytes  = (size_t)NBATCH * NSTRIPE * sizeof(u32);  // 32 KB
  const size_t need = sizeof(WsHdr) + hist_bytes + cand_bytes + stripe_bytes;

  if (ws_size >= need) {
    u32* hist    = (u32*)((char*)d_ws + sizeof(WsHdr));
    u64* cand    = (u64*)((char*)d_ws + sizeof(WsHdr) + hist_bytes);
    u32* stripes = (u32*)((char*)d_ws + sizeof(WsHdr) + hist_bytes + cand_bytes);
    int nz16 = (int)(hist_bytes / 16);
    int pb = (n + 255) / 256;
    k_zero   <<<2048, 256, 0, stream>>>(ws, (f4*)hist, nz16);
    k_hist   <<<pb, 256, 0, stream>>>(batch, scores, n, hist, ws);
    k_scan   <<<1, 64, 0, stream>>>(ws);
    k_stripes<<<512, 256, 0, stream>>>(hist, stripes);
    k_pick2  <<<NBATCH, 256, 0, stream>>>(hist, stripes, ws);
    k_compact<<<pb, 256, 0, stream>>>(batch, scores, n, ws, cand);
    k_final  <<<NBATCH, 256, 0, stream>>>(ws, cand);
  } else {
    k_zero_fb  <<<1, 64, 0, stream>>>(ws);
    k_hist_fb  <<<1024, 256, 0, stream>>>(batch, n, ws);
    k_scan     <<<1, 64, 0, stream>>>(ws);
    k_select_fb<<<NBATCH, 256, 0, stream>>>(scores, ws);
  }

  int blocks = (n + 15) / 16;   // 16 rows per block, 16 float4 per row
  k_apply<<<blocks, 256, 0, stream>>>((const f4*)feats, batch, scores, ws,
                                      (f4*)out, n);
}